// Round 1
// baseline (11.465 us; speedup 1.0000x reference)
//
#include <hip/hip_runtime.h>

// HEX loss collapses analytically: pot factorizes (no i-j coupling), numVar
// cancels edge double-counting, so pMargin[v,b] = sigmoid(fs[b,v]) and
// loss = mean_b softplus(-fs[b, labels[b]]).

#ifndef HEX_B
#define HEX_B 32768
#endif
#ifndef HEX_V
#define HEX_V 256
#endif

__global__ void hex_partial_kernel(const float* __restrict__ fs,
                                   const int* __restrict__ labels,
                                   double* __restrict__ partial,
                                   int Bn, int Vn) {
    __shared__ double sdata[256];
    const int tid = threadIdx.x;
    const int stride = gridDim.x * blockDim.x;
    double s = 0.0;
    for (int b = blockIdx.x * blockDim.x + tid; b < Bn; b += stride) {
        const int lab = labels[b];
        const double x = (double)fs[(size_t)b * (size_t)Vn + (size_t)lab];
        // softplus(-x) = -log(sigmoid(x)), numerically stable split:
        const double l = (x > 0.0) ? log1p(exp(-x)) : (-x + log1p(exp(x)));
        s += l;
    }
    sdata[tid] = s;
    __syncthreads();
    for (int off = blockDim.x >> 1; off > 0; off >>= 1) {
        if (tid < off) sdata[tid] += sdata[tid + off];
        __syncthreads();
    }
    if (tid == 0) partial[blockIdx.x] = sdata[0];
}

__global__ void hex_final_kernel(const double* __restrict__ partial,
                                 int nblocks,
                                 float* __restrict__ out,
                                 int Bn) {
    __shared__ double sdata[256];
    const int tid = threadIdx.x;
    double s = 0.0;
    for (int i = tid; i < nblocks; i += blockDim.x) s += partial[i];
    sdata[tid] = s;
    __syncthreads();
    for (int off = blockDim.x >> 1; off > 0; off >>= 1) {
        if (tid < off) sdata[tid] += sdata[tid + off];
        __syncthreads();
    }
    if (tid == 0) out[0] = (float)(sdata[0] / (double)Bn);
}

extern "C" void kernel_launch(void* const* d_in, const int* in_sizes, int n_in,
                              void* d_out, int out_size, void* d_ws, size_t ws_size,
                              hipStream_t stream) {
    const float* fs = (const float*)d_in[0];
    const int* labels = (const int*)d_in[1];
    float* out = (float*)d_out;

    const int Bn = in_sizes[1];           // 32768 labels
    const int Vn = in_sizes[0] / Bn;      // 256

    const int threads = 256;
    const int blocks = 128;               // 128*256 = 32768 = one thread per sample
    double* partial = (double*)d_ws;      // 128 * 8 B = 1 KiB scratch

    hex_partial_kernel<<<blocks, threads, 0, stream>>>(fs, labels, partial, Bn, Vn);
    hex_final_kernel<<<1, threads, 0, stream>>>(partial, blocks, out, Bn);
}